// Round 3
// baseline (25748.828 us; speedup 1.0000x reference)
//
#include <hip/hip_runtime.h>
#include <hip/hip_fp16.h>

constexpr int kB = 128;
constexpr int kN = 1000;
constexpr int kE = 128;
constexpr int kH = 8;
constexpr float kFP8Scale = 64.f;         // fp8 values stored as v*64
constexpr float kQKScale = 0.25f / 64.f;  // 1/sqrt(16) folded with 1/64
constexpr int kPP = 1028;                 // padded p row stride (floats)

typedef _Float16 h2 __attribute__((ext_vector_type(2)));
typedef float f2 __attribute__((ext_vector_type(2)));

__device__ __forceinline__ h2 pkrtz(float a, float b) {
  return __builtin_bit_cast(h2, __builtin_amdgcn_cvt_pkrtz(a, b));
}

// dot of 4 fp8 elems (packed in u, stored value*64) against 4 f16 elems.
__device__ __forceinline__ float dotq(unsigned u, h2 qa, h2 qb, float s) {
  f2 lo = __builtin_amdgcn_cvt_pk_f32_fp8(u, false);
  f2 hi = __builtin_amdgcn_cvt_pk_f32_fp8(u, true);
  h2 l16 = pkrtz(lo.x, lo.y);
  h2 h16 = pkrtz(hi.x, hi.y);
  s = __builtin_amdgcn_fdot2(l16, qa, s, false);
  s = __builtin_amdgcn_fdot2(h16, qb, s, false);
  return s;
}
// 16-elem fp8 dot (one uint4) against 16 f16 elems in q8[0..7].
__device__ __forceinline__ float dot16(uint4 tq, const h2* q8, float s) {
  s = dotq(tq.x, q8[0], q8[1], s);
  s = dotq(tq.y, q8[2], q8[3], s);
  s = dotq(tq.z, q8[4], q8[5], s);
  s = dotq(tq.w, q8[6], q8[7], s);
  return s;
}

__device__ __forceinline__ float fast_tanh(float x) {
  float t = __expf(2.f * x);
  return 1.f - 2.f / (t + 1.f);
}

__device__ __forceinline__ unsigned char enc_fp8(float v) {
  unsigned p = __builtin_amdgcn_cvt_pk_fp8_f32(v, v, 0, false);
  return (unsigned char)(p & 0xFF);
}

// online-softmax / argmax combine; tie -> smaller node id (jnp.argmax).
__device__ __forceinline__ void combine(float& m, float& s, int& a,
                                        float mo, float so, int ao) {
  bool take = (mo > m) || (mo == m && ao < a);
  float mw = take ? mo : m;
  float ml = take ? m : mo;
  float sw = take ? so : s;
  float sl = take ? s : so;
  s = sw + sl * __expf(ml - mw);
  m = mw;
  a = take ? ao : a;
}

// ---- DPP cross-lane helpers (VALU pipe, not DS) ---------------------------
// ctrl: 0xB1 = quad_perm[1,0,3,2] (xor1), 0x4E = quad_perm[2,3,0,1] (xor2),
// 0x141 = row_half_mirror (xor-equiv across quads within octet),
// 0x128 = row_ror:8 (xor8-equiv within 16-lane row, preserves lane%8).
template <int CTRL>
__device__ __forceinline__ float dpp_bcastf(float x) {
  return __builtin_bit_cast(
      float, __builtin_amdgcn_update_dpp(0, __builtin_bit_cast(int, x), CTRL,
                                         0xf, 0xf, true));
}
template <int CTRL>
__device__ __forceinline__ int dpp_bcasti(int x) {
  return __builtin_amdgcn_update_dpp(0, x, CTRL, 0xf, 0xf, true);
}
template <int CTRL>
__device__ __forceinline__ float dpp_addf(float x) {
  return x + dpp_bcastf<CTRL>(x);
}
template <int CTRL>
__device__ __forceinline__ void dpp_combine(float& m, float& s, int& a) {
  float mo = dpp_bcastf<CTRL>(m);
  float so = dpp_bcastf<CTRL>(s);
  int ao = dpp_bcasti<CTRL>(a);
  combine(m, s, a, mo, so, ao);
}

// LDS-only barrier: drains DS ops, leaves global register-loads in flight.
__device__ __forceinline__ void barrier_lds() {
  asm volatile("s_waitcnt lgkmcnt(0)" ::: "memory");
  __builtin_amdgcn_s_barrier();
  asm volatile("" ::: "memory");
}

// ---------------------------------------------------------------------------
// Kernel A: qkv projection -> fp8 (value*64) k / v / logit_k.
// ---------------------------------------------------------------------------
__global__ __launch_bounds__(384) void qkv_kernel(
    const float* __restrict__ ne, const float* __restrict__ Wqkv,
    const float* __restrict__ bqkv, unsigned char* __restrict__ kq,
    unsigned char* __restrict__ vq, unsigned char* __restrict__ lkq) {
  __shared__ float rows[16 * kE];
  int b = blockIdx.x;
  int n0 = blockIdx.y * 16;
  int ntile = min(16, kN - n0);
  int tid = threadIdx.x;

  for (int idx = tid; idx < ntile * kE; idx += 384)
    rows[idx] = ne[(b * kN + n0) * kE + idx];
  __syncthreads();

  int j = tid;  // 0..383
  float acc[16];
#pragma unroll
  for (int r = 0; r < 16; ++r) acc[r] = 0.f;
  for (int i = 0; i < kE; ++i) {
    float w = Wqkv[i * (3 * kE) + j];
#pragma unroll
    for (int r = 0; r < 16; ++r) acc[r] += rows[r * kE + i] * w;
  }
  float bias = bqkv[j];
  unsigned char* dst;
  int col;
  if (j < kE) { dst = kq; col = j; }
  else if (j < 2 * kE) { dst = vq; col = j - kE; }
  else { dst = lkq; col = j - 2 * kE; }
  for (int r = 0; r < ntile; ++r)
    dst[(size_t)(b * kN + n0 + r) * kE + col] =
        enc_fp8((acc[r] + bias) * kFP8Scale);
}

// ---------------------------------------------------------------------------
// Kernel B: qbase[b] = ge@Wfix + bfix + first@Wstep_top + bstep  (fp32)
// ---------------------------------------------------------------------------
__global__ __launch_bounds__(128) void qbase_kernel(
    const float* __restrict__ ne, const float* __restrict__ ge,
    const float* __restrict__ Wfix, const float* __restrict__ bfix,
    const float* __restrict__ Wstep, const float* __restrict__ bstep,
    float* __restrict__ qbase) {
  __shared__ float g[kE], f[kE];
  int b = blockIdx.x, e = threadIdx.x;
  g[e] = ge[b * kE + e];
  f[e] = ne[(size_t)b * kN * kE + e];  // node 0
  __syncthreads();
  float acc = bfix[e] + bstep[e];
  for (int i = 0; i < kE; ++i)
    acc += g[i] * Wfix[i * kE + e] + f[i] * Wstep[i * kE + e];
  qbase[b * kE + e] = acc;
}

// ---------------------------------------------------------------------------
// Kernel B2: qstep[b,n] = (qbase[b] + ne[b,n] @ Wbot) * kQKScale, f16.
// ---------------------------------------------------------------------------
__global__ __launch_bounds__(128) void qstep_kernel(
    const float* __restrict__ ne, const float* __restrict__ Wstep,
    const float* __restrict__ qbase, __half* __restrict__ qstep) {
  __shared__ float rows[8 * kE];
  int b = blockIdx.x;
  int n0 = blockIdx.y * 8;
  int tid = threadIdx.x;
  const float* Wbot = Wstep + kE * kE;

  for (int idx = tid; idx < 8 * kE; idx += 128)
    rows[idx] = ne[((size_t)b * kN + n0) * kE + idx];
  __syncthreads();

  float acc[8];
#pragma unroll
  for (int r = 0; r < 8; ++r) acc[r] = 0.f;
  for (int i = 0; i < kE; ++i) {
    float w = Wbot[i * kE + tid];
#pragma unroll
    for (int r = 0; r < 8; ++r) acc[r] += rows[r * kE + i] * w;
  }
  float qb = qbase[b * kE + tid];
#pragma unroll
  for (int r = 0; r < 8; ++r)
    qstep[((size_t)b * kN + n0 + r) * kE + tid] =
        __float2half((qb + acc[r]) * kQKScale);
}

// ---------------------------------------------------------------------------
// Kernel C: 999-step rollout, one 1024-thread block per batch element.
// Round-2 structure + full prefetch schedule:
//  * K rows for step s+1 issued in step s's phase 6: every thread knows A
//    (all-thread DPP combine) and computes the PATCHED rem locally
//    (rem changes at exactly one slot per step), so loads cross the barrier
//    in flight (LDS-only barriers).  K latency fully hidden.
//  * V: batches 0-3 issued at phase-1 top (covered by the score dots),
//    batches 4-7 roll depth-4 through the phase-2 consume loop.
//  * logit_k issued mid-phase-2 (after last V issue; issue order == consume
//    order so vmcnt waits never over-drain).
// ---------------------------------------------------------------------------
__global__ __launch_bounds__(1024) void rollout_kernel(
    const float* __restrict__ Wmlp, const float* __restrict__ bmlp,
    const unsigned char* __restrict__ kq, const unsigned char* __restrict__ vq,
    const unsigned char* __restrict__ lkq, const __half* __restrict__ qstep,
    float* __restrict__ out) {
  __shared__ __align__(16) float p[kH][kPP];  // exp(scores), [h][j], 32.9 KB
  __shared__ __align__(16) int rem[1024];     // live node ids (padded)
  __shared__ int pos[kN];                     // node id -> position in rem
  __shared__ float parts[32 * kE];            // ctx half-wave partials, 16 KB
  __shared__ float bm[kE];
  __shared__ __align__(16) float ctx[kE];
  __shared__ __align__(16) __half xh[kE];
  __shared__ float redSum[16][kH];
  __shared__ __align__(16) float4 redPack[16];  // (m, ssum, argbits, -)

  int b = blockIdx.x;
  int tid = threadIdx.x;
  int lane = tid & 63;
  int wave = tid >> 6;
  int g = tid >> 3;    // node-group 0..127
  int t = tid & 7;     // head / uint4 slot within row
  int w2 = tid >> 5;   // half-wave 0..31
  int idx = tid & 31;  // uint index within a 128B row
  int h = idx >> 2;    // head owning elems 4*idx..4*idx+3

  const unsigned char* kqb = kq + (size_t)b * kN * kE;
  const unsigned char* vqb = vq + (size_t)b * kN * kE;
  const unsigned char* lqb = lkq + (size_t)b * kN * kE;
  const __half* qsb = qstep + (size_t)b * kN * kE;

  // x-matvec weight column (output elem g, i-chunk t), register resident
  float wm[16];
#pragma unroll
  for (int i = 0; i < 16; ++i) wm[i] = Wmlp[(t * 16 + i) * kE + g];

  // init live list (rem padded to 1024 with valid ids for safe prefetch)
  rem[tid] = (tid < kN - 1) ? tid + 1 : 1;
  if (tid < kN - 1) pos[tid + 1] = tid;
  if (tid < kE) bm[tid] = bmlp[tid];

  // current action + its q row (prefetched into registers; node 0 first)
  int A = 0;
  uint4 qa, qb_;
  {
    const uint4* qr = (const uint4*)qsb;
    qa = qr[2 * t];
    qb_ = qr[2 * t + 1];
  }
  float total = 0.f;

  barrier_lds();  // init visible

  // step-0 K prefetch (node ids / K rows; carried in registers each step)
  int jn[8];
  uint4 ku[8];
#pragma unroll
  for (int r = 0; r < 8; ++r) {
    int j = g + 128 * r;
    jn[r] = (j < kN - 1) ? rem[j] : -1;
    if (jn[r] >= 0) ku[r] = ((const uint4*)(kqb + (size_t)jn[r] * kE))[t];
  }

  for (int step = 0; step < kN - 1; ++step) {
    int R = kN - 1 - step;  // live count (deterministic)

    // ================= phase 1: scores (K prefetched last step) ==========
    h2 q8[8];
    {
      unsigned qw[8] = {qa.x, qa.y, qa.z, qa.w, qb_.x, qb_.y, qb_.z, qb_.w};
#pragma unroll
      for (int i = 0; i < 8; ++i) q8[i] = __builtin_bit_cast(h2, qw[i]);
    }

    // V prefetch: batches 0..3 (latency hides under the score dots)
    unsigned uu[4][4];
    int jbv[4];
#pragma unroll
    for (int qq = 0; qq < 4; ++qq) {
      int jb = w2 * 4 + 128 * qq;
      jbv[qq] = jb;
      if (jb < R) {
        int4 rm = *(const int4*)(rem + jb);
        uu[qq][0] = ((const unsigned*)(vqb + (size_t)rm.x * kE))[idx];
        uu[qq][1] = ((const unsigned*)(vqb + (size_t)rm.y * kE))[idx];
        uu[qq][2] = ((const unsigned*)(vqb + (size_t)rm.z * kE))[idx];
        uu[qq][3] = ((const unsigned*)(vqb + (size_t)rm.w * kE))[idx];
      }
    }

    float den = 0.f;
#pragma unroll
    for (int r = 0; r < 8; ++r)
      if (jn[r] >= 0) {
        float s = dot16(ku[r], q8, 0.f);
        float hv = __expf(s);  // scores tiny: no max-subtract
        p[t][g + 128 * r] = hv;
        den += hv;
      }
    // den: sum across the 8 groups of this wave (preserve t = lane%8)
    den = dpp_addf<0x128>(den);   // xor8-equiv
    den += __shfl_xor(den, 16);
    den += __shfl_xor(den, 32);
    if (lane < kH) redSum[wave][lane] = den;  // lane==t for lanes 0..7
    barrier_lds();  // B1: p, redSum ready

    // ================= phase 2: ctx partials (depth-4 V pipeline) ========
    uint4 lu[8];
    {
      float a0 = 0.f, a1 = 0.f, a2 = 0.f, a3 = 0.f;
#pragma unroll
      for (int q = 0; q < 8; ++q) {
        const int s = q & 3;
        int jb = jbv[s];
        if (jb < R) {
          float4 pw = *(const float4*)&p[h][jb];
#pragma unroll
          for (int k = 0; k < 4; ++k) {
            if (jb + k < R) {
              unsigned u = uu[s][k];
              float pk = (k == 0) ? pw.x : (k == 1) ? pw.y
                                         : (k == 2) ? pw.z : pw.w;
              f2 lo = __builtin_amdgcn_cvt_pk_f32_fp8(u, false);
              f2 hi = __builtin_amdgcn_cvt_pk_f32_fp8(u, true);
              a0 += pk * lo.x;
              a1 += pk * lo.y;
              a2 += pk * hi.x;
              a3 += pk * hi.y;
            }
          }
        }
        if (q < 4) {  // issue batch q+4 into slot s (depth-4 pipeline)
          int jb2 = w2 * 4 + 128 * (q + 4);
          jbv[s] = jb2;
          if (jb2 < R) {
            int4 rm = *(const int4*)(rem + jb2);
            uu[s][0] = ((const unsigned*)(vqb + (size_t)rm.x * kE))[idx];
            uu[s][1] = ((const unsigned*)(vqb + (size_t)rm.y * kE))[idx];
            uu[s][2] = ((const unsigned*)(vqb + (size_t)rm.z * kE))[idx];
            uu[s][3] = ((const unsigned*)(vqb + (size_t)rm.w * kE))[idx];
          }
        }
        if (q == 3) {
          // logit_k prefetch: after the last V issue so the issue order
          // matches consume order; covered by V consume + phases 3/4.
#pragma unroll
          for (int r = 0; r < 8; ++r)
            if (jn[r] >= 0)
              lu[r] = ((const uint4*)(lqb + (size_t)jn[r] * kE))[t];
        }
      }
      ((float4*)(parts + w2 * kE))[idx] = make_float4(a0, a1, a2, a3);
    }
    barrier_lds();  // B2: parts ready

    // ================= phase 3: finalize ctx (128 threads) ===============
    if (tid < kE) {
      int hh = tid >> 4;
      float d2 = 0.f, s = 0.f;
#pragma unroll
      for (int w = 0; w < 16; ++w) d2 += redSum[w][hh];
#pragma unroll
      for (int w = 0; w < 32; ++w) s += parts[w * kE + tid];
      ctx[tid] = s / (d2 * kFP8Scale);
    }
    barrier_lds();  // B3: ctx ready

    // ================= phase 4: x = (bm + ctx @ Wmlp) * kQKScale =========
    {
      float xacc = 0.f;
      const float4* c4 = (const float4*)(ctx + t * 16);
#pragma unroll
      for (int k4 = 0; k4 < 4; ++k4) {
        float4 cv = c4[k4];
        xacc += cv.x * wm[4 * k4 + 0] + cv.y * wm[4 * k4 + 1] +
                cv.z * wm[4 * k4 + 2] + cv.w * wm[4 * k4 + 3];
      }
      xacc = dpp_addf<0xB1>(xacc);   // xor1
      xacc = dpp_addf<0x4E>(xacc);   // xor2
      xacc = dpp_addf<0x141>(xacc);  // xor4-equiv (octet mirror)
      if (t == 0) xh[g] = __float2half((bm[g] + xacc) * kQKScale);
    }
    barrier_lds();  // B4: xh ready

    // ================= phase 5: logits (lu already in registers) =========
    float m = -1e30f, ssum = 0.f;
    int arg = 0x7fffffff;
    {
      h2 x8[8];
      uint4 xv0 = ((const uint4*)xh)[2 * t];
      uint4 xv1 = ((const uint4*)xh)[2 * t + 1];
      unsigned xw[8] = {xv0.x, xv0.y, xv0.z, xv0.w,
                        xv1.x, xv1.y, xv1.z, xv1.w};
#pragma unroll
      for (int i = 0; i < 8; ++i) x8[i] = __builtin_bit_cast(h2, xw[i]);
#pragma unroll
      for (int r = 0; r < 8; ++r)
        if (jn[r] >= 0) {  // uniform within each 8-lane octet (depends on g)
          float s = dot16(lu[r], x8, 0.f);
          s = dpp_addf<0xB1>(s);
          s = dpp_addf<0x4E>(s);
          s = dpp_addf<0x141>(s);
          if (t == 0) {
            float l = fast_tanh(s) * 10.f;
            combine(m, ssum, arg, l, 1.f, jn[r]);
          }
        }
    }
    // wave butterfly: DPP for 1/2/4/8, shfl for 16/32
    dpp_combine<0xB1>(m, ssum, arg);
    dpp_combine<0x4E>(m, ssum, arg);
    dpp_combine<0x141>(m, ssum, arg);
    dpp_combine<0x128>(m, ssum, arg);
#pragma unroll
    for (int off = 16; off <= 32; off <<= 1) {
      float mo = __shfl_xor(m, off);
      float so = __shfl_xor(ssum, off);
      int ao = __shfl_xor(arg, off);
      combine(m, ssum, arg, mo, so, ao);
    }
    if (lane == 0)
      redPack[wave] = make_float4(m, ssum, __int_as_float(arg), 0.f);
    barrier_lds();  // B5: per-wave reductions ready

    // ====== phase 6: all-thread final combine, q + next-K prefetch =======
    {
      float4 rp = redPack[lane & 15];
      float M = rp.x, S = rp.y;
      int Af = __float_as_int(rp.z);
      dpp_combine<0xB1>(M, S, Af);
      dpp_combine<0x4E>(M, S, Af);
      dpp_combine<0x141>(M, S, Af);
      dpp_combine<0x128>(M, S, Af);
      A = Af;
      total += -logf(S);  // chosen logit == M => log_p[act] = -log S
      // prefetch next q row (every thread knows A; load overlaps barrier)
      const uint4* qr = (const uint4*)(qsb + (size_t)A * kE);
      qa = qr[2 * t];
      qb_ = qr[2 * t + 1];

      // next-step K prefetch using LOCALLY PATCHED rem: the update changes
      // only slot jp (-> lastn).  Race with tid0's LDS write is benign:
      // old-value+patch == new value for every address involved.
      int jp = pos[A];
      int lastn = rem[R - 1];
      int Rn = R - 1;
#pragma unroll
      for (int r = 0; r < 8; ++r) {
        int j = g + 128 * r;
        int nj = (j < Rn) ? ((j == jp) ? lastn : rem[j]) : -1;
        jn[r] = nj;
        if (nj >= 0) ku[r] = ((const uint4*)(kqb + (size_t)nj * kE))[t];
      }
      if (tid == 0) {  // publish swap-remove for future steps
        rem[jp] = lastn;
        pos[lastn] = jp;
      }
    }
    barrier_lds();  // B6: rem/pos updated for next step
  }
  if (tid == 0) out[b] = total;
}

// ---------------------------------------------------------------------------
extern "C" void kernel_launch(void* const* d_in, const int* in_sizes, int n_in,
                              void* d_out, int out_size, void* d_ws,
                              size_t ws_size, hipStream_t stream) {
  const float* ne = (const float*)d_in[0];
  const float* ge = (const float*)d_in[1];
  const float* Wqkv = (const float*)d_in[2];
  const float* bqkv = (const float*)d_in[3];
  const float* Wfix = (const float*)d_in[4];
  const float* bfix = (const float*)d_in[5];
  const float* Wstep = (const float*)d_in[6];
  const float* bstep = (const float*)d_in[7];
  const float* Wmlp = (const float*)d_in[8];
  const float* bmlp = (const float*)d_in[9];
  float* out = (float*)d_out;

  size_t nkv = (size_t)kB * kN * kE;  // bytes per fp8 tensor
  unsigned char* kq = (unsigned char*)d_ws;
  unsigned char* vq = kq + nkv;
  unsigned char* lkq = vq + nkv;
  __half* qstep = (__half*)(lkq + nkv);  // 2*nkv bytes
  float* qbase = (float*)(qstep + nkv);  // 64 KB

  qkv_kernel<<<dim3(kB, (kN + 15) / 16), 384, 0, stream>>>(ne, Wqkv, bqkv, kq,
                                                           vq, lkq);
  qbase_kernel<<<kB, kE, 0, stream>>>(ne, ge, Wfix, bfix, Wstep, bstep, qbase);
  qstep_kernel<<<dim3(kB, kN / 8), 128, 0, stream>>>(ne, Wstep, qbase, qstep);
  rollout_kernel<<<kB, 1024, 0, stream>>>(Wmlp, bmlp, kq, vq, lkq, qstep, out);
}

// Round 4
// 21827.667 us; speedup vs baseline: 1.1796x; 1.1796x over previous
//
#include <hip/hip_runtime.h>
#include <hip/hip_fp16.h>

constexpr int kB = 128;
constexpr int kN = 1000;
constexpr int kE = 128;
constexpr int kH = 8;
constexpr float kFP8Scale = 64.f;         // fp8 values stored as v*64
constexpr float kQKScale = 0.25f / 64.f;  // 1/sqrt(16) folded with 1/64
constexpr int kPP = 1028;                 // padded p row stride (floats)

typedef _Float16 h2 __attribute__((ext_vector_type(2)));
typedef float f2 __attribute__((ext_vector_type(2)));

__device__ __forceinline__ h2 pkrtz(float a, float b) {
  return __builtin_bit_cast(h2, __builtin_amdgcn_cvt_pkrtz(a, b));
}

// dot of 4 fp8 elems (packed in u, stored value*64) against 4 f16 elems.
__device__ __forceinline__ float dotq(unsigned u, h2 qa, h2 qb, float s) {
  f2 lo = __builtin_amdgcn_cvt_pk_f32_fp8(u, false);
  f2 hi = __builtin_amdgcn_cvt_pk_f32_fp8(u, true);
  h2 l16 = pkrtz(lo.x, lo.y);
  h2 h16 = pkrtz(hi.x, hi.y);
  s = __builtin_amdgcn_fdot2(l16, qa, s, false);
  s = __builtin_amdgcn_fdot2(h16, qb, s, false);
  return s;
}
// 16-elem fp8 dot (one uint4) against 16 f16 elems in q8[0..7].
__device__ __forceinline__ float dot16(uint4 tq, const h2* q8, float s) {
  s = dotq(tq.x, q8[0], q8[1], s);
  s = dotq(tq.y, q8[2], q8[3], s);
  s = dotq(tq.z, q8[4], q8[5], s);
  s = dotq(tq.w, q8[6], q8[7], s);
  return s;
}

__device__ __forceinline__ float fast_tanh(float x) {
  float t = __expf(2.f * x);
  return 1.f - 2.f / (t + 1.f);
}

__device__ __forceinline__ unsigned char enc_fp8(float v) {
  unsigned p = __builtin_amdgcn_cvt_pk_fp8_f32(v, v, 0, false);
  return (unsigned char)(p & 0xFF);
}

// online-softmax / argmax combine; tie -> smaller node id (jnp.argmax).
__device__ __forceinline__ void combine(float& m, float& s, int& a,
                                        float mo, float so, int ao) {
  bool take = (mo > m) || (mo == m && ao < a);
  float mw = take ? mo : m;
  float ml = take ? m : mo;
  float sw = take ? so : s;
  float sl = take ? s : so;
  s = sw + sl * __expf(ml - mw);
  m = mw;
  a = take ? ao : a;
}

// ---- DPP cross-lane helpers (VALU pipe, not DS) ---------------------------
// ctrl: 0xB1 = quad_perm[1,0,3,2] (xor1), 0x4E = quad_perm[2,3,0,1] (xor2),
// 0x141 = row_half_mirror (xor-equiv across quads within octet),
// 0x128 = row_ror:8 (xor8-equiv within 16-lane row, preserves lane%8).
template <int CTRL>
__device__ __forceinline__ float dpp_bcastf(float x) {
  return __builtin_bit_cast(
      float, __builtin_amdgcn_update_dpp(0, __builtin_bit_cast(int, x), CTRL,
                                         0xf, 0xf, true));
}
template <int CTRL>
__device__ __forceinline__ int dpp_bcasti(int x) {
  return __builtin_amdgcn_update_dpp(0, x, CTRL, 0xf, 0xf, true);
}
template <int CTRL>
__device__ __forceinline__ float dpp_addf(float x) {
  return x + dpp_bcastf<CTRL>(x);
}
template <int CTRL>
__device__ __forceinline__ void dpp_combine(float& m, float& s, int& a) {
  float mo = dpp_bcastf<CTRL>(m);
  float so = dpp_bcastf<CTRL>(s);
  int ao = dpp_bcasti<CTRL>(a);
  combine(m, s, a, mo, so, ao);
}

// LDS-only barrier: drains DS ops, leaves global register-loads in flight.
__device__ __forceinline__ void barrier_lds() {
  asm volatile("s_waitcnt lgkmcnt(0)" ::: "memory");
  __builtin_amdgcn_s_barrier();
  asm volatile("" ::: "memory");
}

// ---------------------------------------------------------------------------
// Kernel A: qkv projection -> fp8 (value*64) k / v / logit_k.
// ---------------------------------------------------------------------------
__global__ __launch_bounds__(384) void qkv_kernel(
    const float* __restrict__ ne, const float* __restrict__ Wqkv,
    const float* __restrict__ bqkv, unsigned char* __restrict__ kq,
    unsigned char* __restrict__ vq, unsigned char* __restrict__ lkq) {
  __shared__ float rows[16 * kE];
  int b = blockIdx.x;
  int n0 = blockIdx.y * 16;
  int ntile = min(16, kN - n0);
  int tid = threadIdx.x;

  for (int idx = tid; idx < ntile * kE; idx += 384)
    rows[idx] = ne[(b * kN + n0) * kE + idx];
  __syncthreads();

  int j = tid;  // 0..383
  float acc[16];
#pragma unroll
  for (int r = 0; r < 16; ++r) acc[r] = 0.f;
  for (int i = 0; i < kE; ++i) {
    float w = Wqkv[i * (3 * kE) + j];
#pragma unroll
    for (int r = 0; r < 16; ++r) acc[r] += rows[r * kE + i] * w;
  }
  float bias = bqkv[j];
  unsigned char* dst;
  int col;
  if (j < kE) { dst = kq; col = j; }
  else if (j < 2 * kE) { dst = vq; col = j - kE; }
  else { dst = lkq; col = j - 2 * kE; }
  for (int r = 0; r < ntile; ++r)
    dst[(size_t)(b * kN + n0 + r) * kE + col] =
        enc_fp8((acc[r] + bias) * kFP8Scale);
}

// ---------------------------------------------------------------------------
// Kernel B: qbase[b] = ge@Wfix + bfix + first@Wstep_top + bstep  (fp32)
// ---------------------------------------------------------------------------
__global__ __launch_bounds__(128) void qbase_kernel(
    const float* __restrict__ ne, const float* __restrict__ ge,
    const float* __restrict__ Wfix, const float* __restrict__ bfix,
    const float* __restrict__ Wstep, const float* __restrict__ bstep,
    float* __restrict__ qbase) {
  __shared__ float g[kE], f[kE];
  int b = blockIdx.x, e = threadIdx.x;
  g[e] = ge[b * kE + e];
  f[e] = ne[(size_t)b * kN * kE + e];  // node 0
  __syncthreads();
  float acc = bfix[e] + bstep[e];
  for (int i = 0; i < kE; ++i)
    acc += g[i] * Wfix[i * kE + e] + f[i] * Wstep[i * kE + e];
  qbase[b * kE + e] = acc;
}

// ---------------------------------------------------------------------------
// Kernel B2: qstep[b,n] = (qbase[b] + ne[b,n] @ Wbot) * kQKScale, f16.
// ---------------------------------------------------------------------------
__global__ __launch_bounds__(128) void qstep_kernel(
    const float* __restrict__ ne, const float* __restrict__ Wstep,
    const float* __restrict__ qbase, __half* __restrict__ qstep) {
  __shared__ float rows[8 * kE];
  int b = blockIdx.x;
  int n0 = blockIdx.y * 8;
  int tid = threadIdx.x;
  const float* Wbot = Wstep + kE * kE;

  for (int idx = tid; idx < 8 * kE; idx += 128)
    rows[idx] = ne[((size_t)b * kN + n0) * kE + idx];
  __syncthreads();

  float acc[8];
#pragma unroll
  for (int r = 0; r < 8; ++r) acc[r] = 0.f;
  for (int i = 0; i < kE; ++i) {
    float w = Wbot[i * kE + tid];
#pragma unroll
    for (int r = 0; r < 8; ++r) acc[r] += rows[r * kE + i] * w;
  }
  float qb = qbase[b * kE + tid];
#pragma unroll
  for (int r = 0; r < 8; ++r)
    qstep[((size_t)b * kN + n0 + r) * kE + tid] =
        __float2half((qb + acc[r]) * kQKScale);
}

// ---------------------------------------------------------------------------
// Kernel C: 999-step rollout, one 1024-thread block per batch element.
// Round-3 prefetch schedule (K for step s+1 issued in step s's phase 6 via
// locally-patched rem; V 4-at-top depth-4; lu mid-phase-2) PLUS
// amdgpu_waves_per_eu(4,4): forces the VGPR budget to 128 (4 waves/EU is
// all a 1024-thread block can have anyway) so the ~100-reg live set of the
// prefetch schedule fits WITHOUT scratch spills (round-3's failure mode:
// 64-reg budget -> spills -> L2 thrash -> +6GB HBM fetch).
// Also: sibling half-wave ctx partials combined in-register (shfl_xor 32)
// before the LDS store -> parts halved (16 partials), phase-3 reads halved.
// ---------------------------------------------------------------------------
__global__ __launch_bounds__(1024)
__attribute__((amdgpu_waves_per_eu(4, 4))) void rollout_kernel(
    const float* __restrict__ Wmlp, const float* __restrict__ bmlp,
    const unsigned char* __restrict__ kq, const unsigned char* __restrict__ vq,
    const unsigned char* __restrict__ lkq, const __half* __restrict__ qstep,
    float* __restrict__ out) {
  __shared__ __align__(16) float p[kH][kPP];  // exp(scores), [h][j], 32.9 KB
  __shared__ __align__(16) int rem[1024];     // live node ids (padded)
  __shared__ int pos[kN];                     // node id -> position in rem
  __shared__ __align__(16) float parts[16 * kE];  // ctx wave partials, 8 KB
  __shared__ float bm[kE];
  __shared__ __align__(16) float ctx[kE];
  __shared__ __align__(16) __half xh[kE];
  __shared__ float redSum[16][kH];
  __shared__ __align__(16) float4 redPack[16];  // (m, ssum, argbits, -)

  int b = blockIdx.x;
  int tid = threadIdx.x;
  int lane = tid & 63;
  int wave = tid >> 6;
  int g = tid >> 3;    // node-group 0..127
  int t = tid & 7;     // head / uint4 slot within row
  int w2 = tid >> 5;   // half-wave 0..31
  int idx = tid & 31;  // uint index within a 128B row
  int h = idx >> 2;    // head owning elems 4*idx..4*idx+3

  const unsigned char* kqb = kq + (size_t)b * kN * kE;
  const unsigned char* vqb = vq + (size_t)b * kN * kE;
  const unsigned char* lqb = lkq + (size_t)b * kN * kE;
  const __half* qsb = qstep + (size_t)b * kN * kE;

  // x-matvec weight column (output elem g, i-chunk t), register resident
  float wm[16];
#pragma unroll
  for (int i = 0; i < 16; ++i) wm[i] = Wmlp[(t * 16 + i) * kE + g];

  // init live list (rem padded to 1024 with valid ids for safe prefetch)
  rem[tid] = (tid < kN - 1) ? tid + 1 : 1;
  if (tid < kN - 1) pos[tid + 1] = tid;
  if (tid < kE) bm[tid] = bmlp[tid];

  // current action + its q row (prefetched into registers; node 0 first)
  int A = 0;
  uint4 qa, qb_;
  {
    const uint4* qr = (const uint4*)qsb;
    qa = qr[2 * t];
    qb_ = qr[2 * t + 1];
  }
  float total = 0.f;

  barrier_lds();  // init visible

  // step-0 K prefetch (node ids / K rows; carried in registers each step)
  int jn[8];
  uint4 ku[8];
#pragma unroll
  for (int r = 0; r < 8; ++r) {
    int j = g + 128 * r;
    jn[r] = (j < kN - 1) ? rem[j] : -1;
    if (jn[r] >= 0) ku[r] = ((const uint4*)(kqb + (size_t)jn[r] * kE))[t];
  }

  for (int step = 0; step < kN - 1; ++step) {
    int R = kN - 1 - step;  // live count (deterministic)

    // ================= phase 1: scores (K prefetched last step) ==========
    h2 q8[8];
    {
      unsigned qw[8] = {qa.x, qa.y, qa.z, qa.w, qb_.x, qb_.y, qb_.z, qb_.w};
#pragma unroll
      for (int i = 0; i < 8; ++i) q8[i] = __builtin_bit_cast(h2, qw[i]);
    }

    // V prefetch: batches 0..3 (latency hides under the score dots)
    unsigned uu[4][4];
    int jbv[4];
#pragma unroll
    for (int qq = 0; qq < 4; ++qq) {
      int jb = w2 * 4 + 128 * qq;
      jbv[qq] = jb;
      if (jb < R) {
        int4 rm = *(const int4*)(rem + jb);
        uu[qq][0] = ((const unsigned*)(vqb + (size_t)rm.x * kE))[idx];
        uu[qq][1] = ((const unsigned*)(vqb + (size_t)rm.y * kE))[idx];
        uu[qq][2] = ((const unsigned*)(vqb + (size_t)rm.z * kE))[idx];
        uu[qq][3] = ((const unsigned*)(vqb + (size_t)rm.w * kE))[idx];
      }
    }

    float den = 0.f;
#pragma unroll
    for (int r = 0; r < 8; ++r)
      if (jn[r] >= 0) {
        float s = dot16(ku[r], q8, 0.f);
        float hv = __expf(s);  // scores tiny: no max-subtract
        p[t][g + 128 * r] = hv;
        den += hv;
      }
    // den: sum across the 8 groups of this wave (preserve t = lane%8)
    den = dpp_addf<0x128>(den);   // xor8-equiv
    den += __shfl_xor(den, 16);
    den += __shfl_xor(den, 32);
    if (lane < kH) redSum[wave][lane] = den;  // lane==t for lanes 0..7
    barrier_lds();  // B1: p, redSum ready

    // ================= phase 2: ctx partials (depth-4 V pipeline) ========
    uint4 lu[8];
    {
      float a0 = 0.f, a1 = 0.f, a2 = 0.f, a3 = 0.f;
#pragma unroll
      for (int q = 0; q < 8; ++q) {
        const int s = q & 3;
        int jb = jbv[s];
        if (jb < R) {
          float4 pw = *(const float4*)&p[h][jb];
#pragma unroll
          for (int k = 0; k < 4; ++k) {
            if (jb + k < R) {
              unsigned u = uu[s][k];
              float pk = (k == 0) ? pw.x : (k == 1) ? pw.y
                                         : (k == 2) ? pw.z : pw.w;
              f2 lo = __builtin_amdgcn_cvt_pk_f32_fp8(u, false);
              f2 hi = __builtin_amdgcn_cvt_pk_f32_fp8(u, true);
              a0 += pk * lo.x;
              a1 += pk * lo.y;
              a2 += pk * hi.x;
              a3 += pk * hi.y;
            }
          }
        }
        if (q < 4) {  // issue batch q+4 into slot s (depth-4 pipeline)
          int jb2 = w2 * 4 + 128 * (q + 4);
          jbv[s] = jb2;
          if (jb2 < R) {
            int4 rm = *(const int4*)(rem + jb2);
            uu[s][0] = ((const unsigned*)(vqb + (size_t)rm.x * kE))[idx];
            uu[s][1] = ((const unsigned*)(vqb + (size_t)rm.y * kE))[idx];
            uu[s][2] = ((const unsigned*)(vqb + (size_t)rm.z * kE))[idx];
            uu[s][3] = ((const unsigned*)(vqb + (size_t)rm.w * kE))[idx];
          }
        }
        if (q == 3) {
          // logit_k prefetch: after the last V issue so the issue order
          // matches consume order; covered by V consume + phases 3/4.
#pragma unroll
          for (int r = 0; r < 8; ++r)
            if (jn[r] >= 0)
              lu[r] = ((const uint4*)(lqb + (size_t)jn[r] * kE))[t];
        }
      }
      // combine sibling half-wave partials in-register -> 16 partials
      a0 += __shfl_xor(a0, 32);
      a1 += __shfl_xor(a1, 32);
      a2 += __shfl_xor(a2, 32);
      a3 += __shfl_xor(a3, 32);
      if (lane < 32)
        ((float4*)(parts + wave * kE))[idx] = make_float4(a0, a1, a2, a3);
    }
    barrier_lds();  // B2: parts ready

    // ================= phase 3: finalize ctx (128 threads) ===============
    if (tid < kE) {
      int hh = tid >> 4;
      float d2 = 0.f, s = 0.f;
#pragma unroll
      for (int w = 0; w < 16; ++w) d2 += redSum[w][hh];
#pragma unroll
      for (int w = 0; w < 16; ++w) s += parts[w * kE + tid];
      ctx[tid] = s / (d2 * kFP8Scale);
    }
    barrier_lds();  // B3: ctx ready

    // ================= phase 4: x = (bm + ctx @ Wmlp) * kQKScale =========
    {
      float xacc = 0.f;
      const float4* c4 = (const float4*)(ctx + t * 16);
#pragma unroll
      for (int k4 = 0; k4 < 4; ++k4) {
        float4 cv = c4[k4];
        xacc += cv.x * wm[4 * k4 + 0] + cv.y * wm[4 * k4 + 1] +
                cv.z * wm[4 * k4 + 2] + cv.w * wm[4 * k4 + 3];
      }
      xacc = dpp_addf<0xB1>(xacc);   // xor1
      xacc = dpp_addf<0x4E>(xacc);   // xor2
      xacc = dpp_addf<0x141>(xacc);  // xor4-equiv (octet mirror)
      if (t == 0) xh[g] = __float2half((bm[g] + xacc) * kQKScale);
    }
    barrier_lds();  // B4: xh ready

    // ================= phase 5: logits (lu already in registers) =========
    float m = -1e30f, ssum = 0.f;
    int arg = 0x7fffffff;
    {
      h2 x8[8];
      uint4 xv0 = ((const uint4*)xh)[2 * t];
      uint4 xv1 = ((const uint4*)xh)[2 * t + 1];
      unsigned xw[8] = {xv0.x, xv0.y, xv0.z, xv0.w,
                        xv1.x, xv1.y, xv1.z, xv1.w};
#pragma unroll
      for (int i = 0; i < 8; ++i) x8[i] = __builtin_bit_cast(h2, xw[i]);
#pragma unroll
      for (int r = 0; r < 8; ++r)
        if (jn[r] >= 0) {  // uniform within each 8-lane octet (depends on g)
          float s = dot16(lu[r], x8, 0.f);
          s = dpp_addf<0xB1>(s);
          s = dpp_addf<0x4E>(s);
          s = dpp_addf<0x141>(s);
          if (t == 0) {
            float l = fast_tanh(s) * 10.f;
            combine(m, ssum, arg, l, 1.f, jn[r]);
          }
        }
    }
    // wave butterfly: DPP for 1/2/4/8, shfl for 16/32
    dpp_combine<0xB1>(m, ssum, arg);
    dpp_combine<0x4E>(m, ssum, arg);
    dpp_combine<0x141>(m, ssum, arg);
    dpp_combine<0x128>(m, ssum, arg);
#pragma unroll
    for (int off = 16; off <= 32; off <<= 1) {
      float mo = __shfl_xor(m, off);
      float so = __shfl_xor(ssum, off);
      int ao = __shfl_xor(arg, off);
      combine(m, ssum, arg, mo, so, ao);
    }
    if (lane == 0)
      redPack[wave] = make_float4(m, ssum, __int_as_float(arg), 0.f);
    barrier_lds();  // B5: per-wave reductions ready

    // ====== phase 6: all-thread final combine, q + next-K prefetch =======
    {
      float4 rp = redPack[lane & 15];
      float M = rp.x, S = rp.y;
      int Af = __float_as_int(rp.z);
      dpp_combine<0xB1>(M, S, Af);
      dpp_combine<0x4E>(M, S, Af);
      dpp_combine<0x141>(M, S, Af);
      dpp_combine<0x128>(M, S, Af);
      A = Af;
      total += -logf(S);  // chosen logit == M => log_p[act] = -log S
      // prefetch next q row (every thread knows A; load overlaps barrier)
      const uint4* qr = (const uint4*)(qsb + (size_t)A * kE);
      qa = qr[2 * t];
      qb_ = qr[2 * t + 1];

      // next-step K prefetch using LOCALLY PATCHED rem: the update changes
      // only slot jp (-> lastn).  Race with tid0's LDS write is benign:
      // old-value+patch == new value for every address involved.
      int jp = pos[A];
      int lastn = rem[R - 1];
      int Rn = R - 1;
#pragma unroll
      for (int r = 0; r < 8; ++r) {
        int j = g + 128 * r;
        int nj = (j < Rn) ? ((j == jp) ? lastn : rem[j]) : -1;
        jn[r] = nj;
        if (nj >= 0) ku[r] = ((const uint4*)(kqb + (size_t)nj * kE))[t];
      }
      if (tid == 0) {  // publish swap-remove for future steps
        rem[jp] = lastn;
        pos[lastn] = jp;
      }
    }
    barrier_lds();  // B6: rem/pos updated for next step
  }
  if (tid == 0) out[b] = total;
}

// ---------------------------------------------------------------------------
extern "C" void kernel_launch(void* const* d_in, const int* in_sizes, int n_in,
                              void* d_out, int out_size, void* d_ws,
                              size_t ws_size, hipStream_t stream) {
  const float* ne = (const float*)d_in[0];
  const float* ge = (const float*)d_in[1];
  const float* Wqkv = (const float*)d_in[2];
  const float* bqkv = (const float*)d_in[3];
  const float* Wfix = (const float*)d_in[4];
  const float* bfix = (const float*)d_in[5];
  const float* Wstep = (const float*)d_in[6];
  const float* bstep = (const float*)d_in[7];
  const float* Wmlp = (const float*)d_in[8];
  const float* bmlp = (const float*)d_in[9];
  float* out = (float*)d_out;

  size_t nkv = (size_t)kB * kN * kE;  // bytes per fp8 tensor
  unsigned char* kq = (unsigned char*)d_ws;
  unsigned char* vq = kq + nkv;
  unsigned char* lkq = vq + nkv;
  __half* qstep = (__half*)(lkq + nkv);  // 2*nkv bytes
  float* qbase = (float*)(qstep + nkv);  // 64 KB

  qkv_kernel<<<dim3(kB, (kN + 15) / 16), 384, 0, stream>>>(ne, Wqkv, bqkv, kq,
                                                           vq, lkq);
  qbase_kernel<<<kB, kE, 0, stream>>>(ne, ge, Wfix, bfix, Wstep, bstep, qbase);
  qstep_kernel<<<dim3(kB, kN / 8), 128, 0, stream>>>(ne, Wstep, qbase, qstep);
  rollout_kernel<<<kB, 1024, 0, stream>>>(Wmlp, bmlp, kq, vq, lkq, qstep, out);
}

// Round 5
// 13501.747 us; speedup vs baseline: 1.9071x; 1.6167x over previous
//
#include <hip/hip_runtime.h>
#include <hip/hip_fp16.h>

constexpr int kB = 128;
constexpr int kN = 1000;
constexpr int kE = 128;
constexpr int kH = 8;
constexpr float kFP8Scale = 64.f;         // fp8 values stored as v*64
constexpr float kQKScale = 0.25f / 64.f;  // 1/sqrt(16) folded with 1/64
constexpr int kPP = 1028;                 // padded p row stride (floats)
constexpr int kPS = 132;                  // parts row stride (floats, 16B-aligned)

typedef _Float16 h2 __attribute__((ext_vector_type(2)));
typedef float f2 __attribute__((ext_vector_type(2)));

__device__ __forceinline__ h2 pkrtz(float a, float b) {
  return __builtin_bit_cast(h2, __builtin_amdgcn_cvt_pkrtz(a, b));
}

// dot of 4 fp8 elems (packed in u, stored value*64) against 4 f16 elems.
__device__ __forceinline__ float dotq(unsigned u, h2 qa, h2 qb, float s) {
  f2 lo = __builtin_amdgcn_cvt_pk_f32_fp8(u, false);
  f2 hi = __builtin_amdgcn_cvt_pk_f32_fp8(u, true);
  h2 l16 = pkrtz(lo.x, lo.y);
  h2 h16 = pkrtz(hi.x, hi.y);
  s = __builtin_amdgcn_fdot2(l16, qa, s, false);
  s = __builtin_amdgcn_fdot2(h16, qb, s, false);
  return s;
}
// 16-elem fp8 dot (one uint4) against 16 f16 elems in q8[0..7].
__device__ __forceinline__ float dot16(uint4 tq, const h2* q8, float s) {
  s = dotq(tq.x, q8[0], q8[1], s);
  s = dotq(tq.y, q8[2], q8[3], s);
  s = dotq(tq.z, q8[4], q8[5], s);
  s = dotq(tq.w, q8[6], q8[7], s);
  return s;
}

__device__ __forceinline__ float fast_tanh(float x) {
  float t = __expf(2.f * x);
  return 1.f - 2.f / (t + 1.f);
}

__device__ __forceinline__ unsigned char enc_fp8(float v) {
  unsigned p = __builtin_amdgcn_cvt_pk_fp8_f32(v, v, 0, false);
  return (unsigned char)(p & 0xFF);
}

// online-softmax / argmax combine; tie -> smaller node id (jnp.argmax).
__device__ __forceinline__ void combine(float& m, float& s, int& a,
                                        float mo, float so, int ao) {
  bool take = (mo > m) || (mo == m && ao < a);
  float mw = take ? mo : m;
  float ml = take ? m : mo;
  float sw = take ? so : s;
  float sl = take ? s : so;
  s = sw + sl * __expf(ml - mw);
  m = mw;
  a = take ? ao : a;
}

// ---- DPP cross-lane helpers (VALU pipe, not DS) ---------------------------
// ctrl: 0xB1 = quad_perm[1,0,3,2] (xor1), 0x4E = quad_perm[2,3,0,1] (xor2),
// 0x141 = row_half_mirror (xor-equiv across quads within octet),
// 0x128 = row_ror:8 (xor8-equiv within 16-lane row, preserves lane%8).
template <int CTRL>
__device__ __forceinline__ float dpp_bcastf(float x) {
  return __builtin_bit_cast(
      float, __builtin_amdgcn_update_dpp(0, __builtin_bit_cast(int, x), CTRL,
                                         0xf, 0xf, true));
}
template <int CTRL>
__device__ __forceinline__ int dpp_bcasti(int x) {
  return __builtin_amdgcn_update_dpp(0, x, CTRL, 0xf, 0xf, true);
}
template <int CTRL>
__device__ __forceinline__ float dpp_addf(float x) {
  return x + dpp_bcastf<CTRL>(x);
}
template <int CTRL>
__device__ __forceinline__ void dpp_combine(float& m, float& s, int& a) {
  float mo = dpp_bcastf<CTRL>(m);
  float so = dpp_bcastf<CTRL>(s);
  int ao = dpp_bcasti<CTRL>(a);
  combine(m, s, a, mo, so, ao);
}

// LDS-only barrier: drains DS ops, leaves global register-loads in flight.
__device__ __forceinline__ void barrier_lds() {
  asm volatile("s_waitcnt lgkmcnt(0)" ::: "memory");
  __builtin_amdgcn_s_barrier();
  asm volatile("" ::: "memory");
}

// ---------------------------------------------------------------------------
// Kernel A: qkv projection -> fp8 (value*64) k / v / logit_k.
// ---------------------------------------------------------------------------
__global__ __launch_bounds__(384) void qkv_kernel(
    const float* __restrict__ ne, const float* __restrict__ Wqkv,
    const float* __restrict__ bqkv, unsigned char* __restrict__ kq,
    unsigned char* __restrict__ vq, unsigned char* __restrict__ lkq) {
  __shared__ float rows[16 * kE];
  int b = blockIdx.x;
  int n0 = blockIdx.y * 16;
  int ntile = min(16, kN - n0);
  int tid = threadIdx.x;

  for (int idx = tid; idx < ntile * kE; idx += 384)
    rows[idx] = ne[(b * kN + n0) * kE + idx];
  __syncthreads();

  int j = tid;  // 0..383
  float acc[16];
#pragma unroll
  for (int r = 0; r < 16; ++r) acc[r] = 0.f;
  for (int i = 0; i < kE; ++i) {
    float w = Wqkv[i * (3 * kE) + j];
#pragma unroll
    for (int r = 0; r < 16; ++r) acc[r] += rows[r * kE + i] * w;
  }
  float bias = bqkv[j];
  unsigned char* dst;
  int col;
  if (j < kE) { dst = kq; col = j; }
  else if (j < 2 * kE) { dst = vq; col = j - kE; }
  else { dst = lkq; col = j - 2 * kE; }
  for (int r = 0; r < ntile; ++r)
    dst[(size_t)(b * kN + n0 + r) * kE + col] =
        enc_fp8((acc[r] + bias) * kFP8Scale);
}

// ---------------------------------------------------------------------------
// Kernel B: qbase[b] = ge@Wfix + bfix + first@Wstep_top + bstep  (fp32)
// ---------------------------------------------------------------------------
__global__ __launch_bounds__(128) void qbase_kernel(
    const float* __restrict__ ne, const float* __restrict__ ge,
    const float* __restrict__ Wfix, const float* __restrict__ bfix,
    const float* __restrict__ Wstep, const float* __restrict__ bstep,
    float* __restrict__ qbase) {
  __shared__ float g[kE], f[kE];
  int b = blockIdx.x, e = threadIdx.x;
  g[e] = ge[b * kE + e];
  f[e] = ne[(size_t)b * kN * kE + e];  // node 0
  __syncthreads();
  float acc = bfix[e] + bstep[e];
  for (int i = 0; i < kE; ++i)
    acc += g[i] * Wfix[i * kE + e] + f[i] * Wstep[i * kE + e];
  qbase[b * kE + e] = acc;
}

// ---------------------------------------------------------------------------
// Kernel B2: qstep[b,n] = (qbase[b] + ne[b,n] @ Wbot) * kQKScale, f16.
// ---------------------------------------------------------------------------
__global__ __launch_bounds__(128) void qstep_kernel(
    const float* __restrict__ ne, const float* __restrict__ Wstep,
    const float* __restrict__ qbase, __half* __restrict__ qstep) {
  __shared__ float rows[8 * kE];
  int b = blockIdx.x;
  int n0 = blockIdx.y * 8;
  int tid = threadIdx.x;
  const float* Wbot = Wstep + kE * kE;

  for (int idx = tid; idx < 8 * kE; idx += 128)
    rows[idx] = ne[((size_t)b * kN + n0) * kE + idx];
  __syncthreads();

  float acc[8];
#pragma unroll
  for (int r = 0; r < 8; ++r) acc[r] = 0.f;
  for (int i = 0; i < kE; ++i) {
    float w = Wbot[i * kE + tid];
#pragma unroll
    for (int r = 0; r < 8; ++r) acc[r] += rows[r * kE + i] * w;
  }
  float qb = qbase[b * kE + tid];
#pragma unroll
  for (int r = 0; r < 8; ++r)
    qstep[((size_t)b * kN + n0 + r) * kE + tid] =
        __float2half((qb + acc[r]) * kQKScale);
}

// ---------------------------------------------------------------------------
// Kernel C: 999-step rollout, one 1024-thread block per batch element.
// Round-2 proven structure + SORTED live list:
//  * rem[] kept sorted ascending; removal is a parallel shift-left
//    (shift iff id >= A, locally decidable — no pos[], no extra barrier:
//    rem[tid]/rem[tid+1] read at phase-5 top, write after B5).
//    Sorted rem => all K/V/LK gathers are contiguous runs of rows =>
//    full cache-line use, sequential locality, far fewer L2 misses.
//  * phase 3 parallelized over all 1024 threads (4 reads + DPP octet tree).
//  * phase 5: lane t==r captures entry r (no serial combine chain).
//  * lu issued at phase-2 top (more latency cover).
// Cross-barrier register state identical to round 2 (q row only) — the
// 64-VGPR budget (unraisable; rounds 3/4) is respected, no spills.
// ---------------------------------------------------------------------------
__global__ __launch_bounds__(1024) void rollout_kernel(
    const float* __restrict__ Wmlp, const float* __restrict__ bmlp,
    const unsigned char* __restrict__ kq, const unsigned char* __restrict__ vq,
    const unsigned char* __restrict__ lkq, const __half* __restrict__ qstep,
    float* __restrict__ out) {
  __shared__ __align__(16) float p[kH][kPP];     // exp(scores), 32.9 KB
  __shared__ __align__(16) int rem[1024];        // SORTED live ids (padded)
  __shared__ __align__(16) float parts[32 * kPS];  // ctx partials, 16.9 KB
  __shared__ float bm[kE];
  __shared__ __align__(16) float ctx[kE];
  __shared__ __align__(16) __half xh[kE];
  __shared__ float redSum[16][kH];
  __shared__ __align__(16) float4 redPack[16];  // (m, ssum, argbits, -)

  int b = blockIdx.x;
  int tid = threadIdx.x;
  int lane = tid & 63;
  int wave = tid >> 6;
  int g = tid >> 3;    // node-group 0..127
  int t = tid & 7;     // head / uint4 slot within row
  int w2 = tid >> 5;   // half-wave 0..31
  int idx = tid & 31;  // uint index within a 128B row
  int h = idx >> 2;    // head owning elems 4*idx..4*idx+3

  const unsigned char* kqb = kq + (size_t)b * kN * kE;
  const unsigned char* vqb = vq + (size_t)b * kN * kE;
  const unsigned char* lqb = lkq + (size_t)b * kN * kE;
  const __half* qsb = qstep + (size_t)b * kN * kE;

  // x-matvec weight column (output elem g, i-chunk t), register resident
  float wm[16];
#pragma unroll
  for (int i = 0; i < 16; ++i) wm[i] = Wmlp[(t * 16 + i) * kE + g];

  // init sorted live list (padded with valid ids for safe speculative reads)
  rem[tid] = (tid < kN - 1) ? tid + 1 : kN - 1;
  if (tid < kE) bm[tid] = bmlp[tid];

  // current action + its q row (prefetched into registers; node 0 first)
  int A = 0;
  uint4 qa, qb_;
  {
    const uint4* qr = (const uint4*)qsb;
    qa = qr[2 * t];
    qb_ = qr[2 * t + 1];
  }
  float total = 0.f;

  barrier_lds();  // init visible

  for (int step = 0; step < kN - 1; ++step) {
    int R = kN - 1 - step;  // live count (deterministic)

    // ================= phase 1: scores ===================================
    int jn[8];
#pragma unroll
    for (int r = 0; r < 8; ++r) {
      int j = g + 128 * r;
      jn[r] = (j < R) ? rem[j] : -1;
    }
    uint4 ku[8];
#pragma unroll
    for (int r = 0; r < 8; ++r)
      if (jn[r] >= 0) ku[r] = ((const uint4*)(kqb + (size_t)jn[r] * kE))[t];

    // V prefetch: batches 0,1 (latency hides under the score dots); with
    // sorted rem the 4 rows per batch are contiguous memory.
    unsigned uu[2][4];
    int jbv[2];
#pragma unroll
    for (int qq = 0; qq < 2; ++qq) {
      int jb = w2 * 4 + 128 * qq;
      jbv[qq] = jb;
      if (jb < R) {
        int4 rm = *(const int4*)(rem + jb);
        uu[qq][0] = ((const unsigned*)(vqb + (size_t)rm.x * kE))[idx];
        uu[qq][1] = ((const unsigned*)(vqb + (size_t)rm.y * kE))[idx];
        uu[qq][2] = ((const unsigned*)(vqb + (size_t)rm.z * kE))[idx];
        uu[qq][3] = ((const unsigned*)(vqb + (size_t)rm.w * kE))[idx];
      }
    }

    h2 q8[8];
    {
      unsigned qw[8] = {qa.x, qa.y, qa.z, qa.w, qb_.x, qb_.y, qb_.z, qb_.w};
#pragma unroll
      for (int i = 0; i < 8; ++i) q8[i] = __builtin_bit_cast(h2, qw[i]);
    }

    float den = 0.f;
#pragma unroll
    for (int r = 0; r < 8; ++r)
      if (jn[r] >= 0) {
        float s = dot16(ku[r], q8, 0.f);
        float hv = __expf(s);  // scores tiny: no max-subtract
        p[t][g + 128 * r] = hv;
        den += hv;
      }
    // den: sum across the 8 groups of this wave (preserve t = lane%8)
    den = dpp_addf<0x128>(den);   // xor8-equiv
    den += __shfl_xor(den, 16);
    den += __shfl_xor(den, 32);
    if (lane < kH) redSum[wave][lane] = den;  // lane==t for lanes 0..7
    barrier_lds();  // B1: p, redSum ready

    // ================= phase 2: ctx partials (depth-2 V pipeline) ========
    // lu issued first: addresses need only jn; covered by the whole phase
    // plus phases 3/4 before the phase-5 consume.
    uint4 lu[8];
#pragma unroll
    for (int r = 0; r < 8; ++r)
      if (jn[r] >= 0) lu[r] = ((const uint4*)(lqb + (size_t)jn[r] * kE))[t];
    {
      float a0 = 0.f, a1 = 0.f, a2 = 0.f, a3 = 0.f;
#pragma unroll
      for (int q = 0; q < 8; ++q) {
        const int s = q & 1;
        int jb = jbv[s];
        if (jb < R) {
          float4 pw = *(const float4*)&p[h][jb];
#pragma unroll
          for (int k = 0; k < 4; ++k) {
            if (jb + k < R) {
              unsigned u = uu[s][k];
              float pk = (k == 0) ? pw.x : (k == 1) ? pw.y
                                         : (k == 2) ? pw.z : pw.w;
              f2 lo = __builtin_amdgcn_cvt_pk_f32_fp8(u, false);
              f2 hi = __builtin_amdgcn_cvt_pk_f32_fp8(u, true);
              a0 += pk * lo.x;
              a1 += pk * lo.y;
              a2 += pk * hi.x;
              a3 += pk * hi.y;
            }
          }
        }
        if (q + 2 < 8) {  // issue batch q+2 into slot s (depth-2 pipeline)
          int jb2 = w2 * 4 + 128 * (q + 2);
          jbv[s] = jb2;
          if (jb2 < R) {
            int4 rm = *(const int4*)(rem + jb2);
            uu[s][0] = ((const unsigned*)(vqb + (size_t)rm.x * kE))[idx];
            uu[s][1] = ((const unsigned*)(vqb + (size_t)rm.y * kE))[idx];
            uu[s][2] = ((const unsigned*)(vqb + (size_t)rm.z * kE))[idx];
            uu[s][3] = ((const unsigned*)(vqb + (size_t)rm.w * kE))[idx];
          }
        }
      }
      ((float4*)(parts + w2 * kPS))[idx] = make_float4(a0, a1, a2, a3);
    }
    barrier_lds();  // B2: parts ready

    // ====== phase 3: finalize ctx (ALL threads, DPP octet tree) ==========
    {
      int e = tid >> 3, sub = tid & 7, hh = e >> 4;
      float s = 0.f;
#pragma unroll
      for (int w4 = 0; w4 < 4; ++w4) s += parts[(sub + 8 * w4) * kPS + e];
      float d = redSum[sub][hh] + redSum[sub + 8][hh];
      s = dpp_addf<0xB1>(s);
      s = dpp_addf<0x4E>(s);
      s = dpp_addf<0x141>(s);
      d = dpp_addf<0xB1>(d);
      d = dpp_addf<0x4E>(d);
      d = dpp_addf<0x141>(d);
      if (sub == 0) ctx[e] = s / (d * kFP8Scale);
    }
    barrier_lds();  // B3: ctx ready

    // ================= phase 4: x = (bm + ctx @ Wmlp) * kQKScale =========
    {
      float xacc = 0.f;
      const float4* c4 = (const float4*)(ctx + t * 16);
#pragma unroll
      for (int k4 = 0; k4 < 4; ++k4) {
        float4 cv = c4[k4];
        xacc += cv.x * wm[4 * k4 + 0] + cv.y * wm[4 * k4 + 1] +
                cv.z * wm[4 * k4 + 2] + cv.w * wm[4 * k4 + 3];
      }
      xacc = dpp_addf<0xB1>(xacc);   // xor1
      xacc = dpp_addf<0x4E>(xacc);   // xor2
      xacc = dpp_addf<0x141>(xacc);  // xor4-equiv (octet mirror)
      if (t == 0) xh[g] = __float2half((bm[g] + xacc) * kQKScale);
    }
    barrier_lds();  // B4: xh ready

    // ================= phase 5: logits (lu already in registers) =========
    // Read rem[tid]/rem[tid+1] NOW (before B5): B5 is then the read/write
    // fence for the sorted shift-remove in phase 6.
    int myv = rem[tid];
    int nxt = rem[(tid < 1023) ? tid + 1 : 1023];
    float m = -1e30f, ssum = 0.f;
    int arg = 0x7fffffff;
    {
      h2 x8[8];
      uint4 xv0 = ((const uint4*)xh)[2 * t];
      uint4 xv1 = ((const uint4*)xh)[2 * t + 1];
      unsigned xw[8] = {xv0.x, xv0.y, xv0.z, xv0.w,
                        xv1.x, xv1.y, xv1.z, xv1.w};
#pragma unroll
      for (int i = 0; i < 8; ++i) x8[i] = __builtin_bit_cast(h2, xw[i]);
#pragma unroll
      for (int r = 0; r < 8; ++r)
        if (jn[r] >= 0) {  // uniform within each 8-lane octet (depends on g)
          float s = dot16(lu[r], x8, 0.f);
          s = dpp_addf<0xB1>(s);
          s = dpp_addf<0x4E>(s);
          s = dpp_addf<0x141>(s);
          if (t == r) {  // lane t captures entry r: no serial combine chain
            m = fast_tanh(s) * 10.f;
            ssum = 1.f;
            arg = jn[r];
          }
        }
    }
    // wave butterfly: DPP for 1/2/4/8, shfl for 16/32
    dpp_combine<0xB1>(m, ssum, arg);
    dpp_combine<0x4E>(m, ssum, arg);
    dpp_combine<0x141>(m, ssum, arg);
    dpp_combine<0x128>(m, ssum, arg);
#pragma unroll
    for (int off = 16; off <= 32; off <<= 1) {
      float mo = __shfl_xor(m, off);
      float so = __shfl_xor(ssum, off);
      int ao = __shfl_xor(arg, off);
      combine(m, ssum, arg, mo, so, ao);
    }
    if (lane == 0)
      redPack[wave] = make_float4(m, ssum, __int_as_float(arg), 0.f);
    barrier_lds();  // B5: reductions ready; rem reads fenced from writes

    // ====== phase 6: all-thread final combine, q prefetch, shift-remove ==
    {
      float4 rp = redPack[lane & 15];
      float M = rp.x, S = rp.y;
      int Af = __float_as_int(rp.z);
      dpp_combine<0xB1>(M, S, Af);
      dpp_combine<0x4E>(M, S, Af);
      dpp_combine<0x141>(M, S, Af);
      dpp_combine<0x128>(M, S, Af);
      A = Af;
      total += -logf(S);  // chosen logit == M => log_p[act] = -log S
      // prefetch next q row (every thread knows A; load overlaps barrier)
      const uint4* qr = (const uint4*)(qsb + (size_t)A * kE);
      qa = qr[2 * t];
      qb_ = qr[2 * t + 1];
      // sorted shift-remove: positions >= pos(A) shift left by one.
      // Sorted => shift condition is local: id >= A.
      if (tid < R - 1 && myv >= A) rem[tid] = nxt;
    }
    barrier_lds();  // B6: rem updated for next step
  }
  if (tid == 0) out[b] = total;
}

// ---------------------------------------------------------------------------
extern "C" void kernel_launch(void* const* d_in, const int* in_sizes, int n_in,
                              void* d_out, int out_size, void* d_ws,
                              size_t ws_size, hipStream_t stream) {
  const float* ne = (const float*)d_in[0];
  const float* ge = (const float*)d_in[1];
  const float* Wqkv = (const float*)d_in[2];
  const float* bqkv = (const float*)d_in[3];
  const float* Wfix = (const float*)d_in[4];
  const float* bfix = (const float*)d_in[5];
  const float* Wstep = (const float*)d_in[6];
  const float* bstep = (const float*)d_in[7];
  const float* Wmlp = (const float*)d_in[8];
  const float* bmlp = (const float*)d_in[9];
  float* out = (float*)d_out;

  size_t nkv = (size_t)kB * kN * kE;  // bytes per fp8 tensor
  unsigned char* kq = (unsigned char*)d_ws;
  unsigned char* vq = kq + nkv;
  unsigned char* lkq = vq + nkv;
  __half* qstep = (__half*)(lkq + nkv);  // 2*nkv bytes
  float* qbase = (float*)(qstep + nkv);  // 64 KB

  qkv_kernel<<<dim3(kB, (kN + 15) / 16), 384, 0, stream>>>(ne, Wqkv, bqkv, kq,
                                                           vq, lkq);
  qbase_kernel<<<kB, kE, 0, stream>>>(ne, ge, Wfix, bfix, Wstep, bstep, qbase);
  qstep_kernel<<<dim3(kB, kN / 8), 128, 0, stream>>>(ne, Wstep, qbase, qstep);
  rollout_kernel<<<kB, 1024, 0, stream>>>(Wmlp, bmlp, kq, vq, lkq, qstep, out);
}